// Round 6
// baseline (72.794 us; speedup 1.0000x reference)
//
#include <hip/hip_runtime.h>
#include <math.h>

#define SRATE 16000
#define FRAME 320
#define LAGS 189
#define LAG_MIN 5
#define WIN_MED 30
#define BATCH 8
#define TLEN 80000
#define KFRAMES 250           // ceil(80000/320)
#define NOUT 235              // 250 + 14 - 30 + 1
#define NTOT (BATCH * NOUT)   // 1880
#define SEG (FRAME + LAGS)    // 509

// ---------------- Kernel 1: NCCF + best lag + frame energy ----------------
// R6: R5's prefix-scan e2/e1, plus:
//  - inner loop 4x-unrolled with a w0..w3 float4 register ring: zero window
//    moves (was 4 v_mov/iter = 20% of inner VALU). Loads stay 16B-aligned;
//    the deepest load is sh[4*47+240+80+3] = sh[511], in bounds.
//  - combine+argmax merged: waves 0..2 each own 64 lags, compute NCCF
//    in-register from pcr/Sarr, in-wave butterfly reduce, 3-way final.
//    Drops the shv LDS round-trip and one __syncthreads. First-max
//    tie-break preserved (wave lag-partitions are index-ordered).
__global__ __launch_bounds__(256) void nccf_best_kernel(
    const float* __restrict__ audio, int* __restrict__ best,
    float* __restrict__ out) {
  const int k = blockIdx.x;
  const int b = blockIdx.y;
  const float* row = audio + (size_t)b * TLEN;
  const int base = k * FRAME;

  __shared__ float sh[512];        // segment, zero-padded
  __shared__ float Sarr[512];      // inclusive prefix sum of sh[i]^2
  __shared__ float pcr[4][192];    // per-wave partial cross-corr
  __shared__ float wsum[4];        // per-wave scan totals
  __shared__ float pbv[4]; __shared__ int pbi[4];   // per-wave argmax (full)
  __shared__ float phv[4]; __shared__ int phi[4];   // per-wave argmax (half)

  const int tid = threadIdx.x;
  const int w = tid >> 6;
  const int lane = tid & 63;

  // ---- stage 512 floats (beyond SEG or TLEN -> 0) ----
  if (tid < 128) {
    int j = 4 * tid;
    float4 v;
    if (j + 3 < SEG && base + j + 3 < TLEN) {
      v = *(const float4*)(row + base + j);
    } else {
      v.x = (j + 0 < SEG && base + j + 0 < TLEN) ? row[base + j + 0] : 0.0f;
      v.y = (j + 1 < SEG && base + j + 1 < TLEN) ? row[base + j + 1] : 0.0f;
      v.z = (j + 2 < SEG && base + j + 2 < TLEN) ? row[base + j + 2] : 0.0f;
      v.w = (j + 3 < SEG && base + j + 3 < TLEN) ? row[base + j + 3] : 0.0f;
    }
    *(float4*)&sh[j] = v;
  }
  __syncthreads();

  // ---- prefix sum of squares: thread owns pair (2t, 2t+1) ----
  {
    const int t2 = 2 * tid;
    float x0 = sh[t2], x1 = sh[t2 + 1];
    float sq1 = x1 * x1;
    float incl = x0 * x0 + sq1;          // pair sum
    #pragma unroll
    for (int d = 1; d < 64; d <<= 1) {
      float u = __shfl_up(incl, d, 64);
      if (lane >= d) incl += u;
    }
    if (lane == 63) wsum[w] = incl;
    __syncthreads();
    float off = 0.0f;
    if (w > 0) off += wsum[0];
    if (w > 1) off += wsum[1];
    if (w > 2) off += wsum[2];
    float s_hi = off + incl;
    Sarr[t2 + 1] = s_hi;                 // S[2t+1]
    Sarr[t2] = s_hi - sq1;               // S[2t]
  }
  // (sync after inner loop orders Sarr for the combine step)

  // ---- cross-corr: 4 waves split K (80 samples each), lanes 0..47 own
  //      4 consecutive lags; 4x-unrolled register ring, no moves ----
  if (lane < 48) {
    const int i0b = w * 80;
    const float* wp = &sh[4 * lane + i0b];
    float cr[4] = {0.f, 0.f, 0.f, 0.f};
    float4 w0 = *(const float4*)wp;
    float4 w1, w2, w3;
    #define CR_STEP(A, LO, HI)                                         \
      cr[0] += A.x * LO.y + A.y * LO.z + A.z * LO.w + A.w * HI.x;      \
      cr[1] += A.x * LO.z + A.y * LO.w + A.z * HI.x + A.w * HI.y;      \
      cr[2] += A.x * LO.w + A.y * HI.x + A.z * HI.y + A.w * HI.z;      \
      cr[3] += A.x * HI.x + A.y * HI.y + A.z * HI.z + A.w * HI.w;
    #pragma unroll
    for (int ii = 0; ii < 80; ii += 16) {
      float4 a;
      a = *(const float4*)&sh[i0b + ii];
      w1 = *(const float4*)(wp + ii + 4);
      CR_STEP(a, w0, w1);
      a = *(const float4*)&sh[i0b + ii + 4];
      w2 = *(const float4*)(wp + ii + 8);
      CR_STEP(a, w1, w2);
      a = *(const float4*)&sh[i0b + ii + 8];
      w3 = *(const float4*)(wp + ii + 12);
      CR_STEP(a, w2, w3);
      a = *(const float4*)&sh[i0b + ii + 12];
      w0 = *(const float4*)(wp + ii + 16);
      CR_STEP(a, w3, w0);
    }
    #undef CR_STEP
    *(float4*)&pcr[w][4 * lane] = *(float4*)cr;
  }
  __syncthreads();

  // ---- merged combine + argmax: waves 0..2 own one lag per lane ----
  {
    float bv = -INFINITY; int bi = 999;
    float hv = -INFINITY; int hi2 = 999;
    const int ll = (w << 6) + lane;          // 0..255; valid lags < 189
    if (w < 3 && ll < LAGS) {
      float crs = pcr[0][ll] + pcr[1][ll] + pcr[2][ll] + pcr[3][ll];
      float e2s = Sarr[ll + 320] - Sarr[ll]; // sum sh[ll+1..ll+320]^2
      if (e2s < 0.0f) e2s = 0.0f;            // guard 1-ulp negatives
      float e1s = Sarr[319];                 // sum sh[0..319]^2
      float d1 = 1e-9f + sqrtf(e1s);
      float d2 = 1e-9f + sqrtf(e2s);
      float v = crs / (d1 * d1) / (d2 * d2);
      if (ll >= LAG_MIN) { bv = v; bi = ll; }
      if (ll >= LAG_MIN && ll < (LAGS / 2)) { hv = v; hi2 = ll; }
      if (tid == 0) out[3 * NTOT + b * KFRAMES + k] = e1s * (1.0f / FRAME);
    }
    #pragma unroll
    for (int off = 32; off >= 1; off >>= 1) {
      float ov = __shfl_xor(bv, off, 64);
      int   oi = __shfl_xor(bi, off, 64);
      if (ov > bv || (ov == bv && oi < bi)) { bv = ov; bi = oi; }
      float ohv = __shfl_xor(hv, off, 64);
      int   ohi = __shfl_xor(hi2, off, 64);
      if (ohv > hv || (ohv == hv && ohi < hi2)) { hv = ohv; hi2 = ohi; }
    }
    if (lane == 0) { pbv[w] = bv; pbi[w] = bi; phv[w] = hv; phi[w] = hi2; }
    __syncthreads();
    if (tid == 0) {
      float Bv = pbv[0]; int Bi = pbi[0];
      float Hv = phv[0]; int Hi = phi[0];
      #pragma unroll
      for (int j2 = 1; j2 < 3; ++j2) {
        if (pbv[j2] > Bv || (pbv[j2] == Bv && pbi[j2] < Bi)) { Bv = pbv[j2]; Bi = pbi[j2]; }
        if (phv[j2] > Hv || (phv[j2] == Hv && phi[j2] < Hi)) { Hv = phv[j2]; Hi = phi[j2]; }
      }
      int chosen = (Hv > 0.99f * Bv) ? Hi : Bi;
      best[b * KFRAMES + k] = chosen + 1;
    }
  }
}

// ---------------- Kernel 2: median smoothing (one wave per output) --------
__global__ __launch_bounds__(256) void median_f0_kernel(
    const int* __restrict__ best, float* __restrict__ out) {
  const int w = blockIdx.x * 4 + (threadIdx.x >> 6);   // wave id = output id
  const int lane = threadIdx.x & 63;
  const int b = w / NOUT;
  const int t = w - b * NOUT;

  int v = 0x7fffffff;
  if (lane < WIN_MED) {
    int j = t + lane - 14;               // left replicate-pad by 14
    if (j < 0) j = 0;
    v = best[b * KFRAMES + j];
  }
  int c_lt = 0, c_le = 0;
  #pragma unroll
  for (int j = 0; j < WIN_MED; ++j) {
    int bv = __shfl(v, j, 64);
    c_lt += (bv < v) ? 1 : 0;
    c_le += (bv <= v) ? 1 : 0;
  }
  // lower median = sorted[14]: value with count(<v) <= 14 < count(<=v)
  bool cond = (lane < WIN_MED) && (c_lt <= 14) && (c_le > 14);
  unsigned long long m = __ballot(cond);
  int sel = __ffsll((long long)m) - 1;
  int med = __shfl(v, sel, 64);
  if (lane == 0) {
    float f0 = 16000.0f / (1e-9f + (float)med);
    out[b * NOUT + t] = f0;              // f0
    out[2 * NTOT + b * NOUT + t] = 1.0f; // voiced (f0 > 0 always)
  }
}

// ---------------- Kernel 3: whiten (1 block x 1024: reduce + apply) -------
// 1024 threads: 2 grid-stride iters (was 8) + shuffle reduce. Double-
// precision accumulation; order differs from R5 but error ~1e-15 vs a
// float32 reference with a generous threshold.
__global__ __launch_bounds__(1024) void whiten_kernel(float* __restrict__ out) {
  __shared__ double reds[16], reds2[16];
  __shared__ float fmean_s, finvsd_s;
  const int t = threadIdx.x;
  double s = 0.0, s2 = 0.0;
  float fv[2] = {0.f, 0.f};
  int nv = 0;
  for (int i = t; i < NTOT; i += 1024) {
    float f = out[i];
    fv[nv++] = f;
    double d = (double)f;
    s += d; s2 += d * d;
  }
  #pragma unroll
  for (int off = 32; off >= 1; off >>= 1) {
    s  += __shfl_down(s,  off, 64);
    s2 += __shfl_down(s2, off, 64);
  }
  if ((t & 63) == 0) { reds[t >> 6] = s; reds2[t >> 6] = s2; }
  __syncthreads();
  if (t == 0) {
    double S = 0.0, S2 = 0.0;
    #pragma unroll
    for (int i = 0; i < 16; ++i) { S += reds[i]; S2 += reds2[i]; }
    const double n = (double)NTOT;
    double mean = S / n;
    double var = (S2 - n * mean * mean) / (n - 1.0);
    if (var < 0.0) var = 0.0;
    double sd = sqrt(var);
    fmean_s = (float)mean;
    finvsd_s = (sd == 0.0) ? 1.0f : (float)(1.0 / sd);
  }
  __syncthreads();
  float fmean = fmean_s, finvsd = finvsd_s;
  nv = 0;
  for (int i = t; i < NTOT; i += 1024) {
    out[NTOT + i] = (fv[nv++] - fmean) * finvsd;
  }
}

extern "C" void kernel_launch(void* const* d_in, const int* in_sizes, int n_in,
                              void* d_out, int out_size, void* d_ws, size_t ws_size,
                              hipStream_t stream) {
  const float* audio = (const float*)d_in[0];
  float* out = (float*)d_out;
  int* best = (int*)d_ws;   // 2000 ints

  dim3 g1(KFRAMES, BATCH);
  nccf_best_kernel<<<g1, 256, 0, stream>>>(audio, best, out);
  median_f0_kernel<<<(NTOT + 3) / 4, 256, 0, stream>>>(best, out);
  whiten_kernel<<<1, 1024, 0, stream>>>(out);
}